// Round 9
// baseline (809.120 us; speedup 1.0000x reference)
//
#include <hip/hip_runtime.h>
#include <hip/hip_bf16.h>

#define NN 1000000
#define NG 15625   // NN / 64 nodes per group

typedef short bf16x8 __attribute__((ext_vector_type(8)));
typedef float f32x4  __attribute__((ext_vector_type(4)));
typedef unsigned short u16x8 __attribute__((ext_vector_type(8)));
typedef unsigned short u16x4 __attribute__((ext_vector_type(4)));

__device__ __forceinline__ float bf2f(unsigned short u){
  unsigned int x = ((unsigned int)u) << 16; float f;
  __builtin_memcpy(&f, &x, 4); return f;
}
__device__ __forceinline__ short f2bf(float v){
  __hip_bfloat16 h = __float2bfloat16(v); short s;
  __builtin_memcpy(&s, &h, 2); return s;
}

// ---------------- Layer 2: h1(bf16)[1M,128] -> out(f32)[1M,128] ----------------
// 512 thr = 8 waves; group = 64 nodes; wave w owns cols [w*16, w*16+16).
// selfS staged by global_load_lds (linear LDS dest, PRE-SWIZZLED global source),
// TWO 16B DMA items per thread (1024 items = 64 nodes x 16 chunks — R8 bug was 1).
// aggS gathered through registers (mask+mean needs VALU anyway). Plain out stores.
__global__ __launch_bounds__(512, 2) void sage2_mfma(
    const unsigned short* __restrict__ h1, const float* __restrict__ W2,
    const int* __restrict__ nidx, const int* __restrict__ nmask,
    float* __restrict__ out)
{
  __shared__ unsigned short selfS[2][64 * 128];   // 2 x 16 KB, dbuf (DMA target)
  __shared__ unsigned short aggS[64 * 128];       // 16 KB
  __shared__ float red[64][8];
  const int t   = threadIdx.x;
  const int l   = t & 63;
  const int w   = t >> 6;       // 0..7
  const int cfr = l & 15;
  const int kg  = l >> 4;

  // B frags: col = w*16+cfr; Bf[ks] covers k = ks*32+kg*8..+7 (k<128 self, else agg)
  bf16x8 Bf[8];
  #pragma unroll
  for (int ks = 0; ks < 8; ++ks) {
    const int col = w*16 + cfr;
    const float* p = W2 + col*256 + ks*32 + kg*8;
    f32x4 a = *reinterpret_cast<const f32x4*>(p);
    f32x4 b = *reinterpret_cast<const f32x4*>(p + 4);
    bf16x8 v;
    v[0]=f2bf(a[0]); v[1]=f2bf(a[1]); v[2]=f2bf(a[2]); v[3]=f2bf(a[3]);
    v[4]=f2bf(b[0]); v[5]=f2bf(b[1]); v[6]=f2bf(b[2]); v[7]=f2bf(b[3]);
    Bf[ks] = v;
  }

  const u16x8* hp = reinterpret_cast<const u16x8*>(h1);

  int nib0[2], nib1[2], nib2[2], nmb0[2], nmb1[2], nmb2[2];
  u16x8 s0[2], s1[2], s2[2];
  float m0[2], m1[2], m2[2], iv[2];

  auto IDX = [&](int g){
    const long gb = (long)g * 64;
    #pragma unroll
    for (int i = 0; i < 2; ++i) {
      int nn = (t + i*512) >> 4;
      long node = gb + nn;
      nib0[i] = nidx[node*3+0]; nib1[i] = nidx[node*3+1]; nib2[i] = nidx[node*3+2];
      nmb0[i] = nmask[node*3+0]; nmb1[i] = nmask[node*3+1]; nmb2[i] = nmask[node*3+2];
    }
  };
  auto GATHER = [&](int g){
    #pragma unroll
    for (int i = 0; i < 2; ++i) {
      int it = t + i*512;
      int qq = it & 15;
      int b0 = nmb0[i], b1 = nmb1[i], b2 = nmb2[i];
      m0[i]=(float)b0; m1[i]=(float)b1; m2[i]=(float)b2;
      int c = b0+b1+b2; iv[i] = 1.0f/(float)(c<1?1:c);
      u16x8 z = {};
      s0[i] = b0 ? hp[(long)nib0[i]*16 + qq] : z;
      s1[i] = b1 ? hp[(long)nib1[i]*16 + qq] : z;
      s2[i] = b2 ? hp[(long)nib2[i]*16 + qq] : z;
    }
  };
  // Direct DMA of self rows: 2 items/thread, item it = t + i*512 -> (node it>>4,
  // chunk it&15). LDS dest LINEAR at it*16 bytes (wave-uniform base + lane*16);
  // global source chunk pre-swizzled (q ^ (n&7)) to match the MFMA ds_read swizzle.
  auto SELF_DMA = [&](int g, int pp){
    #pragma unroll
    for (int i = 0; i < 2; ++i) {
      int it = t + i*512;
      int nn = it >> 4, qq0 = it & 15;
      long node = (long)g * 64 + nn;
      int qq = qq0 ^ (nn & 7);
      const unsigned short* gp = h1 + node*128 + qq*8;
      unsigned short* lp = &selfS[pp][it*8];
      __builtin_amdgcn_global_load_lds(
          (const __attribute__((address_space(1))) unsigned short*)gp,
          (__attribute__((address_space(3))) unsigned short*)lp, 16, 0, 0);
    }
  };
  char* aggB = reinterpret_cast<char*>(aggS);
  auto UNPACK_AGG = [&](){
    #pragma unroll
    for (int i = 0; i < 2; ++i) {
      int it = t + i*512;
      int nn = it >> 4, qq = it & 15;
      int sw = (nn & 7) << 4;
      u16x8 r;
      #pragma unroll
      for (int j = 0; j < 8; ++j)
        r[j] = (unsigned short)f2bf(
            (m0[i]*bf2f(s0[i][j]) + m1[i]*bf2f(s1[i][j]) + m2[i]*bf2f(s2[i][j])) * iv[i]);
      *reinterpret_cast<u16x8*>(aggB + nn*256 + ((qq*16) ^ sw)) = r;
    }
  };

  const int g0 = blockIdx.x;
  IDX(g0); GATHER(g0); SELF_DMA(g0, 0);
  if (g0 + (int)gridDim.x < NG) IDX(g0 + gridDim.x);

  int p = 0;
  for (int g = g0; g < NG; g += gridDim.x) {
    const long gb = (long)g * 64;
    UNPACK_AGG();
    __syncthreads();                   // aggS + selfS[p] ready (barrier drains DMA)

    int g1 = g + gridDim.x, g2 = g + 2*gridDim.x;
    if (g1 < NG) { GATHER(g1); SELF_DMA(g1, p ^ 1); }
    if (g2 < NG) IDX(g2);

    f32x4 acc[4];
    #pragma unroll
    for (int r = 0; r < 4; ++r) acc[r] = (f32x4){0.f,0.f,0.f,0.f};
    const int swz = (cfr & 7) << 4;
    char* selfB = reinterpret_cast<char*>(selfS) + p*(64*256);
    #pragma unroll
    for (int r = 0; r < 4; ++r) {
      const int rb = (r*16 + cfr) * 256;
      #pragma unroll
      for (int ks = 0; ks < 4; ++ks) {
        bf16x8 af = *reinterpret_cast<const bf16x8*>(selfB + rb + ((ks*64 + kg*16) ^ swz));
        acc[r] = __builtin_amdgcn_mfma_f32_16x16x32_bf16(af, Bf[ks], acc[r], 0,0,0);
      }
      #pragma unroll
      for (int ks = 0; ks < 4; ++ks) {
        bf16x8 af = *reinterpret_cast<const bf16x8*>(aggB + rb + ((ks*64 + kg*16) ^ swz));
        acc[r] = __builtin_amdgcn_mfma_f32_16x16x32_bf16(af, Bf[ks + 4], acc[r], 0,0,0);
      }
    }

    float ssv[4][4];
    #pragma unroll
    for (int r = 0; r < 4; ++r) {
      #pragma unroll
      for (int e = 0; e < 4; ++e) {
        float v = fmaxf(acc[r][e], 0.f); acc[r][e] = v;
        float s = v*v;
        s += __shfl_xor(s, 1); s += __shfl_xor(s, 2);
        s += __shfl_xor(s, 4); s += __shfl_xor(s, 8);
        ssv[r][e] = s;
      }
      if (cfr < 4) {
        float v = cfr==0 ? ssv[r][0] : cfr==1 ? ssv[r][1] : cfr==2 ? ssv[r][2] : ssv[r][3];
        red[r*16 + kg*4 + cfr][w] = v;
      }
    }
    __syncthreads();

    #pragma unroll
    for (int r = 0; r < 4; ++r) {
      #pragma unroll
      for (int e = 0; e < 4; ++e) {
        int row = r*16 + kg*4 + e;
        f32x4 ra = *reinterpret_cast<const f32x4*>(&red[row][0]);
        f32x4 rb4 = *reinterpret_cast<const f32x4*>(&red[row][4]);
        float tot = (ra[0]+ra[1]) + (ra[2]+ra[3]) + (rb4[0]+rb4[1]) + (rb4[2]+rb4[3]);
        float inv = 1.0f / fmaxf(sqrtf(tot), 1e-12f);
        out[(gb + row)*128 + w*16 + cfr] = acc[r][e] * inv;
      }
    }
    p ^= 1;
  }
}

// ---------------- Layer 1: x(f32)[1M,57] -> h1(bf16)[1M,128] ----------------
// Proven R2 shape + VECTORIZED gathers: 16B memcpy loads (4/item) instead of 16
// scalar 4B loads. q==14 tail = 1 scalar (j=56); q==15 item skipped entirely.
// LDS K-layout: [0,57)=self, [57,64)=dead, [64,121)=agg, [121,128)=dead.
// Dead zones k=60..63 / k=124..127 zero-initialized ONCE (q=15 slots never
// rewritten); k=57..59 / 121..123 zeroed every iter by the q==14 store.
__global__ __launch_bounds__(256, 2) void sage1_mfma(
    const float* __restrict__ x, const float* __restrict__ W1,
    const int* __restrict__ nidx, const int* __restrict__ nmask,
    unsigned short* __restrict__ h1)
{
  __shared__ unsigned short comb[64 * 128];
  __shared__ float red[64][4];
  const int t   = threadIdx.x;
  const int l   = t & 63;
  const int w   = t >> 6;
  const int cfr = l & 15;
  const int kg  = l >> 4;

  // B fragments, K remapped: lds_k<57 -> k=lds_k; 64<=lds_k<121 -> k=lds_k-7.
  bf16x8 Bf[4][2];
  #pragma unroll
  for (int ks = 0; ks < 4; ++ks) {
    #pragma unroll
    for (int nf = 0; nf < 2; ++nf) {
      const int col = w*32 + nf*16 + cfr;
      const int k0  = ks*32 + kg*8;
      bf16x8 v;
      #pragma unroll
      for (int j = 0; j < 8; ++j) {
        int lk = k0 + j;
        int wk = lk < 64 ? lk : lk - 7;
        bool valid = (lk < 57) || (lk >= 64 && lk < 121);
        v[j] = valid ? f2bf(W1[col*114 + wk]) : (short)0;
      }
      Bf[ks][nf] = v;
    }
  }

  char* cb = reinterpret_cast<char*>(comb);

  // one-time zero of dead zones k=60..63 (self q=15) and k=124..127 (agg q=15)
  for (int e = t; e < 128; e += 256) {
    int nn = e >> 1, h = e & 1;
    int chunk = h ? 15 : 7;
    int u = chunk ^ (nn & 7);
    *reinterpret_cast<u16x4*>(cb + nn*256 + u*16 + 8) = (u16x4){0,0,0,0};
  }
  __syncthreads();

  f32x4 sf[4], n0[4], n1[4], n2[4];
  float m0[4], m1[4], m2[4], iv[4];

  auto ISSUE = [&](int g){
    const long gb = (long)g * 64;
    #pragma unroll
    for (int i = 0; i < 4; ++i) {
      int it = t + i*256;
      int nn = it >> 4, qq = it & 15;
      long node = gb + nn;
      int j0 = nidx[node*3+0], j1 = nidx[node*3+1], j2 = nidx[node*3+2];
      int b0 = nmask[node*3+0], b1 = nmask[node*3+1], b2 = nmask[node*3+2];
      m0[i]=(float)b0; m1[i]=(float)b1; m2[i]=(float)b2;
      int c = b0+b1+b2; iv[i] = 1.0f/(float)(c<1?1:c);
      f32x4 z = {0.f,0.f,0.f,0.f};
      sf[i]=z; n0[i]=z; n1[i]=z; n2[i]=z;
      if (qq < 14) {                          // j = 4q..4q+3, all < 57
        __builtin_memcpy(&sf[i], x + node*57 + qq*4, 16);
        if (b0) __builtin_memcpy(&n0[i], x + (long)j0*57 + qq*4, 16);
        if (b1) __builtin_memcpy(&n1[i], x + (long)j1*57 + qq*4, 16);
        if (b2) __builtin_memcpy(&n2[i], x + (long)j2*57 + qq*4, 16);
      } else if (qq == 14) {                  // only j=56 valid
        sf[i][0] = x[node*57 + 56];
        if (b0) n0[i][0] = x[(long)j0*57 + 56];
        if (b1) n1[i][0] = x[(long)j1*57 + 56];
        if (b2) n2[i][0] = x[(long)j2*57 + 56];
      }                                       // qq==15: nothing (dead zone)
    }
  };

  if (blockIdx.x < NG) ISSUE(blockIdx.x);

  for (int g = blockIdx.x; g < NG; g += gridDim.x) {
    const long gb = (long)g * 64;
    #pragma unroll
    for (int i = 0; i < 4; ++i) {
      int it = t + i*256;
      int nn = it >> 4, qq = it & 15;
      if (qq < 15) {
        int sw = (nn & 7) << 4;
        u16x4 vs, va;
        #pragma unroll
        for (int jj = 0; jj < 4; ++jj) {
          vs[jj] = (unsigned short)f2bf(sf[i][jj]);
          va[jj] = (unsigned short)f2bf(
              (m0[i]*n0[i][jj] + m1[i]*n1[i][jj] + m2[i]*n2[i][jj]) * iv[i]);
        }
        *reinterpret_cast<u16x4*>(cb + nn*256 + ((qq*8) ^ sw))       = vs;
        *reinterpret_cast<u16x4*>(cb + nn*256 + ((128 + qq*8) ^ sw)) = va;
      }
    }
    __syncthreads();

    int gn = g + gridDim.x;
    if (gn < NG) ISSUE(gn);

    f32x4 acc[4][2];
    #pragma unroll
    for (int r = 0; r < 4; ++r) {
      acc[r][0] = (f32x4){0.f,0.f,0.f,0.f};
      acc[r][1] = (f32x4){0.f,0.f,0.f,0.f};
    }
    const int swz = (cfr & 7) << 4;
    #pragma unroll
    for (int r = 0; r < 4; ++r) {
      const int rb = (r*16 + cfr) * 256;
      #pragma unroll
      for (int ks = 0; ks < 4; ++ks) {
        bf16x8 af = *reinterpret_cast<const bf16x8*>(cb + rb + ((ks*64 + kg*16) ^ swz));
        acc[r][0] = __builtin_amdgcn_mfma_f32_16x16x32_bf16(af, Bf[ks][0], acc[r][0], 0,0,0);
        acc[r][1] = __builtin_amdgcn_mfma_f32_16x16x32_bf16(af, Bf[ks][1], acc[r][1], 0,0,0);
      }
    }

    float ssv[4][4];
    #pragma unroll
    for (int r = 0; r < 4; ++r) {
      #pragma unroll
      for (int e = 0; e < 4; ++e) {
        float v0 = fmaxf(acc[r][0][e], 0.f); acc[r][0][e] = v0;
        float v1 = fmaxf(acc[r][1][e], 0.f); acc[r][1][e] = v1;
        float s = v0*v0 + v1*v1;
        s += __shfl_xor(s, 1); s += __shfl_xor(s, 2);
        s += __shfl_xor(s, 4); s += __shfl_xor(s, 8);
        ssv[r][e] = s;
      }
      if (cfr < 4) {
        float v = cfr==0 ? ssv[r][0] : cfr==1 ? ssv[r][1] : cfr==2 ? ssv[r][2] : ssv[r][3];
        red[r*16 + kg*4 + cfr][w] = v;
      }
    }
    __syncthreads();

    #pragma unroll
    for (int r = 0; r < 4; ++r) {
      #pragma unroll
      for (int e = 0; e < 4; ++e) {
        int row = r*16 + kg*4 + e;
        float tot = red[row][0] + red[row][1] + red[row][2] + red[row][3];
        float inv = 1.0f / fmaxf(sqrtf(tot), 1e-12f);
        long node = gb + row;
        h1[node*128 + w*32 + cfr]      = (unsigned short)f2bf(acc[r][0][e] * inv);
        h1[node*128 + w*32 + 16 + cfr] = (unsigned short)f2bf(acc[r][1][e] * inv);
      }
    }
  }
}

extern "C" void kernel_launch(void* const* d_in, const int* in_sizes, int n_in,
                              void* d_out, int out_size, void* d_ws, size_t ws_size,
                              hipStream_t stream) {
  const float* x   = (const float*)d_in[0];
  const float* W1  = (const float*)d_in[1];
  const float* W2  = (const float*)d_in[2];
  const int* idx1  = (const int*)d_in[3];
  const int* msk1  = (const int*)d_in[4];
  const int* idx2  = (const int*)d_in[5];
  const int* msk2  = (const int*)d_in[6];
  float* out = (float*)d_out;
  unsigned short* h1 = (unsigned short*)d_ws;   // bf16 [1M,128] = 256 MB

  sage1_mfma<<<2048, 256, 0, stream>>>(x, W1, idx1, msk1, h1);
  sage2_mfma<<<512,  512, 0, stream>>>(h1, W2, idx2, msk2, out);
}

// Round 10
// 743.011 us; speedup vs baseline: 1.0890x; 1.0890x over previous
//
#include <hip/hip_runtime.h>
#include <hip/hip_bf16.h>

#define NN 1000000
#define NG 15625   // NN / 64 nodes per group

typedef _Float16 f16x8 __attribute__((ext_vector_type(8)));
typedef _Float16 h2    __attribute__((ext_vector_type(2)));
typedef float f32x4    __attribute__((ext_vector_type(4)));
typedef unsigned short u16x8 __attribute__((ext_vector_type(8)));
typedef unsigned short u16x4 __attribute__((ext_vector_type(4)));

__device__ __forceinline__ unsigned short f2h(float v){
  _Float16 h = (_Float16)v; unsigned short s;
  __builtin_memcpy(&s, &h, 2); return s;
}

// ---------------- Layer 2: h1(fp16)[1M,128] -> out(f32)[1M,128] ----------------
// R5-proven structure (357us): 512 thr = 8 waves, 64-node groups, dbuf comb,
// all-register gather stash, (512,2) -> 128-VGPR cap. NEW: fp16 everywhere —
// agg mean in PACKED fp16 (v_pk_fma_f16), MFMA 16x16x32_f16.
__global__ __launch_bounds__(512, 2) void sage2_mfma(
    const unsigned short* __restrict__ h1, const float* __restrict__ W2,
    const int* __restrict__ nidx, const int* __restrict__ nmask,
    float* __restrict__ out)
{
  __shared__ unsigned short comb[2][64 * 256];   // double-buffered, XOR-swizzled
  __shared__ float red[64][8];
  const int t   = threadIdx.x;
  const int l   = t & 63;
  const int w   = t >> 6;       // 0..7
  const int cfr = l & 15;
  const int kg  = l >> 4;

  // B frags (fp16): col = w*16 + cfr, Bf[ks] covers k = ks*32 + kg*8 .. +7
  f16x8 Bf[8];
  #pragma unroll
  for (int ks = 0; ks < 8; ++ks) {
    const int col = w*16 + cfr;
    const float* p = W2 + col*256 + ks*32 + kg*8;
    f32x4 a = *reinterpret_cast<const f32x4*>(p);
    f32x4 b = *reinterpret_cast<const f32x4*>(p + 4);
    f16x8 v;
    v[0]=(_Float16)a[0]; v[1]=(_Float16)a[1]; v[2]=(_Float16)a[2]; v[3]=(_Float16)a[3];
    v[4]=(_Float16)b[0]; v[5]=(_Float16)b[1]; v[6]=(_Float16)b[2]; v[7]=(_Float16)b[3];
    Bf[ks] = v;
  }

  const u16x8* hp = reinterpret_cast<const u16x8*>(h1);

  int nib0[2], nib1[2], nib2[2], nmb0[2], nmb1[2], nmb2[2];
  u16x8 sS[2], s0[2], s1[2], s2[2];
  _Float16 m0h[2], m1h[2], m2h[2], ivh[2];

  auto IDX = [&](int g){
    const long gb = (long)g * 64;
    #pragma unroll
    for (int i = 0; i < 2; ++i) {
      int n = (t + i*512) >> 4;
      long node = gb + n;
      nib0[i] = nidx[node*3+0]; nib1[i] = nidx[node*3+1]; nib2[i] = nidx[node*3+2];
      nmb0[i] = nmask[node*3+0]; nmb1[i] = nmask[node*3+1]; nmb2[i] = nmask[node*3+2];
    }
  };
  auto GATHER = [&](int g){
    const long gb = (long)g * 64;
    #pragma unroll
    for (int i = 0; i < 2; ++i) {
      int it = t + i*512;
      int n = it >> 4, q = it & 15;
      long node = gb + n;
      int b0 = nmb0[i], b1 = nmb1[i], b2 = nmb2[i];
      m0h[i]=(_Float16)(float)b0; m1h[i]=(_Float16)(float)b1; m2h[i]=(_Float16)(float)b2;
      int c = b0+b1+b2; ivh[i] = (_Float16)(1.0f/(float)(c<1?1:c));
      u16x8 z = {};
      sS[i] = hp[node*16 + q];
      s0[i] = b0 ? hp[(long)nib0[i]*16 + q] : z;   // exec-masked: skip fetch when masked
      s1[i] = b1 ? hp[(long)nib1[i]*16 + q] : z;
      s2[i] = b2 ? hp[(long)nib2[i]*16 + q] : z;
    }
  };
  auto UNPACK = [&](int p){
    char* cb = reinterpret_cast<char*>(comb[p]);
    #pragma unroll
    for (int i = 0; i < 2; ++i) {
      int it = t + i*512;
      int n = it >> 4, q = it & 15;
      int sw = (n & 7) << 4;
      *reinterpret_cast<u16x8*>(cb + n*512 + ((q*16) ^ sw)) = sS[i];
      // agg mean in packed fp16: 4 pk-ops per 2 elements
      h2 A[4], B4[4], C4[4], R[4];
      __builtin_memcpy(A,  &s0[i], 16);
      __builtin_memcpy(B4, &s1[i], 16);
      __builtin_memcpy(C4, &s2[i], 16);
      h2 M0 = {m0h[i], m0h[i]}, M1 = {m1h[i], m1h[i]},
         M2 = {m2h[i], m2h[i]}, IV = {ivh[i], ivh[i]};
      #pragma unroll
      for (int j = 0; j < 4; ++j)
        R[j] = (A[j]*M0 + B4[j]*M1 + C4[j]*M2) * IV;
      u16x8 r; __builtin_memcpy(&r, R, 16);
      *reinterpret_cast<u16x8*>(cb + n*512 + ((256 + q*16) ^ sw)) = r;
    }
  };

  const int g0 = blockIdx.x;
  IDX(g0); GATHER(g0);
  if (g0 + (int)gridDim.x < NG) IDX(g0 + gridDim.x);

  int p = 0;
  for (int g = g0; g < NG; g += gridDim.x) {
    const long gb = (long)g * 64;
    UNPACK(p);
    __syncthreads();                   // buf p ready

    int g1 = g + gridDim.x, g2 = g + 2*gridDim.x;
    if (g1 < NG) GATHER(g1);           // loads in flight across MFMA
    if (g2 < NG) IDX(g2);

    f32x4 acc[4];
    #pragma unroll
    for (int r = 0; r < 4; ++r) acc[r] = (f32x4){0.f,0.f,0.f,0.f};
    const int swz = (cfr & 7) << 4;
    char* cbp = reinterpret_cast<char*>(comb[p]);
    #pragma unroll
    for (int r = 0; r < 4; ++r) {
      const int rb = (r*16 + cfr) * 512;
      #pragma unroll
      for (int ks = 0; ks < 8; ++ks) {
        f16x8 af = *reinterpret_cast<const f16x8*>(cbp + rb + ((ks*64 + kg*16) ^ swz));
        acc[r] = __builtin_amdgcn_mfma_f32_16x16x32_f16(af, Bf[ks], acc[r], 0,0,0);
      }
    }

    float ssv[4][4];
    #pragma unroll
    for (int r = 0; r < 4; ++r) {
      #pragma unroll
      for (int e = 0; e < 4; ++e) {
        float v = fmaxf(acc[r][e], 0.f); acc[r][e] = v;
        float s = v*v;
        s += __shfl_xor(s, 1); s += __shfl_xor(s, 2);
        s += __shfl_xor(s, 4); s += __shfl_xor(s, 8);
        ssv[r][e] = s;
      }
      if (cfr < 4) {
        float v = cfr==0 ? ssv[r][0] : cfr==1 ? ssv[r][1] : cfr==2 ? ssv[r][2] : ssv[r][3];
        red[r*16 + kg*4 + cfr][w] = v;
      }
    }
    __syncthreads();

    #pragma unroll
    for (int r = 0; r < 4; ++r) {
      #pragma unroll
      for (int e = 0; e < 4; ++e) {
        int row = r*16 + kg*4 + e;
        f32x4 ra = *reinterpret_cast<const f32x4*>(&red[row][0]);
        f32x4 rb4 = *reinterpret_cast<const f32x4*>(&red[row][4]);
        float tot = (ra[0]+ra[1]) + (ra[2]+ra[3]) + (rb4[0]+rb4[1]) + (rb4[2]+rb4[3]);
        float inv = 1.0f / fmaxf(sqrtf(tot), 1e-12f);
        out[(gb + row)*128 + w*16 + cfr] = acc[r][e] * inv;
      }
    }
    p ^= 1;
  }
}

// ---------------- Layer 1: x(f32)[1M,57] -> h1(fp16)[1M,128] ----------------
// R7-proven structure (277us): 256 thr, 64-node groups, scalar jv-guarded
// gathers (x rows are 228B — unaligned; 16B vectorization regressed in R9),
// grid 2048, (256,2). Only change: fp16 comb/W1-frags/h1, MFMA f16.
// LDS K-layout: [0,57)=self, [57,64)=0, [64,121)=agg, [121,128)=0.
__global__ __launch_bounds__(256, 2) void sage1_mfma(
    const float* __restrict__ x, const float* __restrict__ W1,
    const int* __restrict__ nidx, const int* __restrict__ nmask,
    unsigned short* __restrict__ h1)
{
  __shared__ unsigned short comb[64 * 128];
  __shared__ float red[64][4];
  const int t   = threadIdx.x;
  const int l   = t & 63;
  const int w   = t >> 6;
  const int cfr = l & 15;
  const int kg  = l >> 4;

  // B fragments (fp16), K remapped: lds_k<57 -> k=lds_k; 64<=lds_k<121 -> k=lds_k-7.
  f16x8 Bf[4][2];
  #pragma unroll
  for (int ks = 0; ks < 4; ++ks) {
    #pragma unroll
    for (int nf = 0; nf < 2; ++nf) {
      const int col = w*32 + nf*16 + cfr;
      const int k0  = ks*32 + kg*8;
      f16x8 v;
      #pragma unroll
      for (int j = 0; j < 8; ++j) {
        int lk = k0 + j;
        int wk = lk < 64 ? lk : lk - 7;
        bool valid = (lk < 57) || (lk >= 64 && lk < 121);
        v[j] = valid ? (_Float16)W1[col*114 + wk] : (_Float16)0.0f;
      }
      Bf[ks][nf] = v;
    }
  }

  char* cb = reinterpret_cast<char*>(comb);

  f32x4 sf[4], n0[4], n1[4], n2[4];
  float m0[4], m1[4], m2[4], iv[4];

  auto ISSUE = [&](int g){
    const long gb = (long)g * 64;
    #pragma unroll
    for (int i = 0; i < 4; ++i) {
      int it = t + i*256;
      int n = it >> 4, q = it & 15;
      long node = gb + n;
      int j0 = nidx[node*3+0], j1 = nidx[node*3+1], j2 = nidx[node*3+2];
      int b0 = nmask[node*3+0], b1 = nmask[node*3+1], b2 = nmask[node*3+2];
      m0[i]=(float)b0; m1[i]=(float)b1; m2[i]=(float)b2;
      int c = b0+b1+b2; iv[i] = 1.0f/(float)(c<1?1:c);
      #pragma unroll
      for (int jj = 0; jj < 4; ++jj) {
        int j = q*4 + jj;
        bool jv = j < 57;
        sf[i][jj] = jv         ? x[node*57 + j]     : 0.f;
        n0[i][jj] = (b0 && jv) ? x[(long)j0*57 + j] : 0.f;
        n1[i][jj] = (b1 && jv) ? x[(long)j1*57 + j] : 0.f;
        n2[i][jj] = (b2 && jv) ? x[(long)j2*57 + j] : 0.f;
      }
    }
  };

  if (blockIdx.x < NG) ISSUE(blockIdx.x);

  for (int g = blockIdx.x; g < NG; g += gridDim.x) {
    const long gb = (long)g * 64;
    #pragma unroll
    for (int i = 0; i < 4; ++i) {
      int it = t + i*256;
      int n = it >> 4, q = it & 15;
      int sw = (n & 7) << 4;
      u16x4 vs, va;
      #pragma unroll
      for (int jj = 0; jj < 4; ++jj) {
        vs[jj] = f2h(sf[i][jj]);
        va[jj] = f2h((m0[i]*n0[i][jj] + m1[i]*n1[i][jj] + m2[i]*n2[i][jj]) * iv[i]);
      }
      *reinterpret_cast<u16x4*>(cb + n*256 + ((q*8) ^ sw))       = vs;
      *reinterpret_cast<u16x4*>(cb + n*256 + ((128 + q*8) ^ sw)) = va;
    }
    __syncthreads();

    int gn = g + gridDim.x;
    if (gn < NG) ISSUE(gn);

    f32x4 acc[4][2];
    #pragma unroll
    for (int r = 0; r < 4; ++r) {
      acc[r][0] = (f32x4){0.f,0.f,0.f,0.f};
      acc[r][1] = (f32x4){0.f,0.f,0.f,0.f};
    }
    const int swz = (cfr & 7) << 4;
    #pragma unroll
    for (int r = 0; r < 4; ++r) {
      const int rb = (r*16 + cfr) * 256;
      #pragma unroll
      for (int ks = 0; ks < 4; ++ks) {
        f16x8 af = *reinterpret_cast<const f16x8*>(cb + rb + ((ks*64 + kg*16) ^ swz));
        acc[r][0] = __builtin_amdgcn_mfma_f32_16x16x32_f16(af, Bf[ks][0], acc[r][0], 0,0,0);
        acc[r][1] = __builtin_amdgcn_mfma_f32_16x16x32_f16(af, Bf[ks][1], acc[r][1], 0,0,0);
      }
    }

    float ssv[4][4];
    #pragma unroll
    for (int r = 0; r < 4; ++r) {
      #pragma unroll
      for (int e = 0; e < 4; ++e) {
        float v0 = fmaxf(acc[r][0][e], 0.f); acc[r][0][e] = v0;
        float v1 = fmaxf(acc[r][1][e], 0.f); acc[r][1][e] = v1;
        float s = v0*v0 + v1*v1;
        s += __shfl_xor(s, 1); s += __shfl_xor(s, 2);
        s += __shfl_xor(s, 4); s += __shfl_xor(s, 8);
        ssv[r][e] = s;
      }
      if (cfr < 4) {
        float v = cfr==0 ? ssv[r][0] : cfr==1 ? ssv[r][1] : cfr==2 ? ssv[r][2] : ssv[r][3];
        red[r*16 + kg*4 + cfr][w] = v;
      }
    }
    __syncthreads();

    #pragma unroll
    for (int r = 0; r < 4; ++r) {
      #pragma unroll
      for (int e = 0; e < 4; ++e) {
        int row = r*16 + kg*4 + e;
        float tot = red[row][0] + red[row][1] + red[row][2] + red[row][3];
        float inv = 1.0f / fmaxf(sqrtf(tot), 1e-12f);
        long node = gb + row;
        h1[node*128 + w*32 + cfr]      = f2h(acc[r][0][e] * inv);
        h1[node*128 + w*32 + 16 + cfr] = f2h(acc[r][1][e] * inv);
      }
    }
  }
}

extern "C" void kernel_launch(void* const* d_in, const int* in_sizes, int n_in,
                              void* d_out, int out_size, void* d_ws, size_t ws_size,
                              hipStream_t stream) {
  const float* x   = (const float*)d_in[0];
  const float* W1  = (const float*)d_in[1];
  const float* W2  = (const float*)d_in[2];
  const int* idx1  = (const int*)d_in[3];
  const int* msk1  = (const int*)d_in[4];
  const int* idx2  = (const int*)d_in[5];
  const int* msk2  = (const int*)d_in[6];
  float* out = (float*)d_out;
  unsigned short* h1 = (unsigned short*)d_ws;   // fp16 [1M,128] = 256 MB

  sage1_mfma<<<2048, 256, 0, stream>>>(x, W1, idx1, msk1, h1);
  sage2_mfma<<<512,  512, 0, stream>>>(h1, W2, idx2, msk2, out);
}